// Round 6
// baseline (463.815 us; speedup 1.0000x reference)
//
#include <hip/hip_runtime.h>

// Problem constants
#define BSZ  128
#define TT   50
#define CIN  2312
#define HID  300
#define NOUT 10
#define KS   5
#define T1   51          // (TT+5) - KS + 1
#define T2   52          // (T1+5) - KS + 1

#define NC32 73          // ceil(CIN/32) K-chunks of 32
#define KFRAG_U 20480    // u16 units per (ow,chunk): 5k * 4nt * 2h * 512

typedef unsigned int u32;
typedef unsigned short u16;
typedef __attribute__((ext_vector_type(8))) short s16x8;   // 8 bf16 (4 VGPRs)
typedef __attribute__((ext_vector_type(4))) float f32x4;   // MFMA C/D

// exp(-k^2/8) constants, k=1..4 (fp32)
#define EK1f 0.88249690258459546f
#define EK2f 0.60653065971263342f
#define EK3f 0.32465246735834974f
#define EK4f 0.13533528323661270f

static __device__ __forceinline__ u16 bfhi(float x) {
  u32 u = __float_as_uint(x);
  return (u16)((u + 0x7fffu + ((u >> 16) & 1u)) >> 16);   // RNE bf16
}
static __device__ __forceinline__ float bf2f(u16 h) {
  return __uint_as_float(((u32)h) << 16);
}

// ===========================================================================
// prep: synthesize gauss kernel once, split into bf16 hi/lo, in exact MFMA
// B-fragment order: [ow][chunk][k][nt][h][lane][8] (frag = 64 lanes x 16 B).
// ===========================================================================
__global__ __launch_bounds__(256) void snn_prepm(
    const float* __restrict__ W1, const float* __restrict__ P1,
    u16* __restrict__ K1bf)
{
  const int c  = blockIdx.x;          // 0..72
  const int ow = blockIdx.y;          // 0..4
  const int tid = threadIdx.x;
  const int nt = tid >> 6, ll = tid & 63;
  const int g = ll >> 4, lr = ll & 15;
  const int o  = ow * 64 + nt * 16 + lr;
  const int ib = c * 32 + g * 8;

  s16x8 hv[5], lv[5];
#pragma unroll
  for (int k = 0; k < 5; ++k)
#pragma unroll
    for (int j = 0; j < 8; ++j) { hv[k][j] = 0; lv[k][j] = 0; }

  if (o < HID) {
    const float* wrow = W1 + (size_t)o * CIN;
    const float* prow = P1 + (size_t)o * CIN;
#pragma unroll
    for (int j = 0; j < 8; ++j) {
      const int i = ib + j;
      if (i < CIN) {
        const float w1 = wrow[i], p1 = prow[i];
        const float cc = p1 + 2.0f;
        const float E0 = __expf(-0.125f * cc * cc);
        const float U  = __expf(0.25f * cc);
        const float u2 = U * U;
        const float e0 = E0;
        const float e1 = E0 * U * EK1f;
        const float e2 = E0 * u2 * EK2f;
        const float e3 = E0 * (u2 * U) * EK3f;
        const float e4 = E0 * (u2 * u2) * EK4f;
        const float inv = 1.0f / (((((e0 + e1) + e2) + e3) + e4) + 1e-7f);
        const float vk[5] = { w1 * (e0 * inv), w1 * (e1 * inv),
                              w1 * (e2 * inv), w1 * (e3 * inv),
                              w1 * (e4 * inv) };
#pragma unroll
        for (int k = 0; k < 5; ++k) {
          const u16 h = bfhi(vk[k]);
          const u16 lo = bfhi(vk[k] - bf2f(h));
          hv[k][j] = (short)h; lv[k][j] = (short)lo;
        }
      }
    }
  }
  u16* base = K1bf + ((size_t)ow * NC32 + c) * KFRAG_U + nt * 1024 + ll * 8;
#pragma unroll
  for (int k = 0; k < 5; ++k) {
    *(s16x8*)(base + k * 4096)       = hv[k];
    *(s16x8*)(base + k * 4096 + 512) = lv[k];
  }
}

// ===========================================================================
// Layer-1 MFMA path, v3.
// Per block (ow,b): C[64 t][64 o], mfma_f32_16x16x32_bf16, 3-term bf16 split.
// Wave grid 1x4: wave w owns ALL 64 t rows (4 m-tiles) x 16 o cols (nt = w)
//   -> zero B-fragment duplication across waves (halves L2 B traffic), and
//      each B frag feeds 12 MFMAs.
// B: 10 frags/wave/chunk, DOUBLE-SET registers, pair-unrolled loop: all 10
//    loads for chunk c+1 issued at the START of chunk c -> complete well
//    before the barrier (no vmcnt-drain stall, rule: counted-style prefetch).
// A: 64(+4 pad)-slot time window x 32 i, bf16 hi/lo, double-buffered LDS,
//    XOR-swizzled (off ^= ((row&3)<<3) u16) on both write and read -> breaks
//    the stride-80B bank pattern (round-5's 1.79e7 conflicts).
// fp64 promotion once per chunk-pair. XCD swizzle: ow-major per XCD.
// LDS: A bufs 2 x (hi 2720 + lo 2720) u16 = 21760 B; y1s double[51][64]
//      overlays after the loop (26112 B total).
// ===========================================================================
__global__ __launch_bounds__(256, 2) void snn_l1m(
    const float* __restrict__ data, const u16* __restrict__ K1bf,
    const float* __restrict__ b1v, u32* __restrict__ gbits)
{
  __shared__ double dsm[3264];         // 26112 B
  u16* A16 = (u16*)dsm;

  const int tid = threadIdx.x;
  const int bid = blockIdx.x;
  const int rnk = (bid & 7) * 80 + (bid >> 3);   // bijective, 640 = 8*80
  const int ow = rnk >> 7;                        // 0..4 (ow-major per XCD)
  const int b  = rnk & 127;

  const int w  = tid >> 6, l = tid & 63;
  const int lr = l & 15, lg = l >> 4;

  const float* dbase = data + (size_t)b * (TT * CIN);
  const u16* kbw = K1bf + (size_t)ow * NC32 * KFRAG_U + w * 1024 + l * 8;

  // A staging thread mapping: slot s1 (0..63), i-group j4 (0..3)
  const int s1 = tid >> 2;
  const int j4 = tid & 3;
  const int tp = s1 - 5;
  const bool avld = (tp >= 0) && (tp < TT);
  const float* aptr = dbase + (size_t)(avld ? tp : 0) * CIN + j4 * 8;

  // ---- zero pad rows 64..67 (tap overhang) in both buffers, hi+lo ----
  if (tid < 64) {
    s16x8 z;
#pragma unroll
    for (int j = 0; j < 8; ++j) z[j] = 0;
    const int r = tid >> 4, sub = tid & 15;
    const int row = 64 + (sub >> 2), off = (sub & 3) * 8;
    *(s16x8*)(A16 + (r >> 1) * 5440 + (r & 1) * 2720 + row * 40 + off) = z;
  }

  // ---- B register sets ----
  s16x8 bh0[5], bl0[5], bh1[5], bl1[5];

#define ISSUE_B(DH, DL, CC)                                                   \
  {                                                                           \
    const u16* cb_ = kbw + (size_t)(CC) * KFRAG_U;                            \
    _Pragma("unroll")                                                         \
    for (int k = 0; k < 5; ++k) {                                             \
      DH[k] = *(const s16x8*)(cb_ + k * 4096);                                \
      DL[k] = *(const s16x8*)(cb_ + k * 4096 + 512);                          \
    }                                                                         \
  }

#define STAGE_A(CC)                                                           \
  {                                                                           \
    const float f_[8] = { ra0.x, ra0.y, ra0.z, ra0.w,                         \
                          ra1.x, ra1.y, ra1.z, ra1.w };                       \
    s16x8 hv_, lv_;                                                           \
    _Pragma("unroll")                                                         \
    for (int j = 0; j < 8; ++j) {                                             \
      const u16 h_ = bfhi(f_[j]);                                             \
      hv_[j] = (short)h_;                                                     \
      lv_[j] = (short)bfhi(f_[j] - bf2f(h_));                                 \
    }                                                                         \
    u16* bn_ = A16 + (((CC) + 1) & 1) * 5440;                                 \
    const int woff_ = s1 * 40 + ((j4 * 8) ^ ((s1 & 3) << 3));                 \
    *(s16x8*)(bn_ + woff_) = hv_;                                             \
    *(s16x8*)(bn_ + 2720 + woff_) = lv_;                                      \
    const int cn_ = ((CC) + 2 <= 72) ? (CC) + 2 : 72;                         \
    const bool iv_ = avld && ((cn_ < 72) || (j4 == 0));                       \
    const float* pp_ = aptr + (size_t)cn_ * 32;                               \
    ra0 = iv_ ? *(const float4*)(pp_)     : make_float4(0.f, 0.f, 0.f, 0.f);  \
    ra1 = iv_ ? *(const float4*)(pp_ + 4) : make_float4(0.f, 0.f, 0.f, 0.f);  \
  }

#define COMPUTE(BH, BL, CC)                                                   \
  {                                                                           \
    const u16* bc_ = A16 + ((CC) & 1) * 5440;                                 \
    _Pragma("unroll")                                                         \
    for (int k = 0; k < 5; ++k) {                                             \
      const int xk_ = ((lr + k) & 3) << 3;                                    \
      const int a0_ = (lr + k) * 40 + ((lg * 8) ^ xk_);                       \
      _Pragma("unroll")                                                       \
      for (int m = 0; m < 4; ++m) {                                           \
        const s16x8 ah_ = *(const s16x8*)(bc_ + a0_ + m * 640);               \
        const s16x8 al_ = *(const s16x8*)(bc_ + 2720 + a0_ + m * 640);        \
        accf[m] = __builtin_amdgcn_mfma_f32_16x16x32_bf16(ah_, BH[k], accf[m], 0, 0, 0); \
        accf[m] = __builtin_amdgcn_mfma_f32_16x16x32_bf16(al_, BH[k], accf[m], 0, 0, 0); \
        accf[m] = __builtin_amdgcn_mfma_f32_16x16x32_bf16(ah_, BL[k], accf[m], 0, 0, 0); \
      }                                                                       \
    }                                                                         \
  }

#define PROMOTE()                                                             \
  _Pragma("unroll")                                                           \
  for (int m = 0; m < 4; ++m)                                                 \
    _Pragma("unroll")                                                         \
    for (int q = 0; q < 4; ++q) {                                             \
      accd[m][q] += (double)accf[m][q];                                       \
      accf[m][q] = 0.f;                                                       \
    }

  f32x4 accf[4];
  double accd[4][4];
#pragma unroll
  for (int m = 0; m < 4; ++m)
#pragma unroll
    for (int q = 0; q < 4; ++q) { accf[m][q] = 0.f; accd[m][q] = 0.0; }

  // ---- prologue: B set0 <- chunk 0; A chunk 0 -> buf0; ra <- chunk 1 ----
  ISSUE_B(bh0, bl0, 0);
  float4 ra0, ra1;
  ra0 = avld ? *(const float4*)(aptr)     : make_float4(0.f, 0.f, 0.f, 0.f);
  ra1 = avld ? *(const float4*)(aptr + 4) : make_float4(0.f, 0.f, 0.f, 0.f);
  {
    const float f_[8] = { ra0.x, ra0.y, ra0.z, ra0.w,
                          ra1.x, ra1.y, ra1.z, ra1.w };
    s16x8 hv_, lv_;
#pragma unroll
    for (int j = 0; j < 8; ++j) {
      const u16 h_ = bfhi(f_[j]);
      hv_[j] = (short)h_;
      lv_[j] = (short)bfhi(f_[j] - bf2f(h_));
    }
    const int woff_ = s1 * 40 + ((j4 * 8) ^ ((s1 & 3) << 3));
    *(s16x8*)(A16 + woff_) = hv_;
    *(s16x8*)(A16 + 2720 + woff_) = lv_;
  }
  {
    const float* pp_ = aptr + 32;
    ra0 = avld ? *(const float4*)(pp_)     : make_float4(0.f, 0.f, 0.f, 0.f);
    ra1 = avld ? *(const float4*)(pp_ + 4) : make_float4(0.f, 0.f, 0.f, 0.f);
  }
  __syncthreads();

  // ---- main loop: 36 pairs (chunks 0..71) + tail chunk 72 ----
  for (int pr = 0; pr < 36; ++pr) {
    const int c0 = 2 * pr, c1 = c0 + 1;
    // even chunk c0: compute set0, prefetch set1 <- c0+1
    ISSUE_B(bh1, bl1, c0 + 1);
    STAGE_A(c0);
    COMPUTE(bh0, bl0, c0);
    __syncthreads();
    // odd chunk c1: compute set1, prefetch set0 <- c1+1
    ISSUE_B(bh0, bl0, c1 + 1);
    STAGE_A(c1);
    COMPUTE(bh1, bl1, c1);
    PROMOTE();
    __syncthreads();
  }
  // tail chunk 72 (buf parity 0, set0 loaded during chunk 71)
  COMPUTE(bh0, bl0, 72);
  PROMOTE();
  __syncthreads();

#undef ISSUE_B
#undef STAGE_A
#undef COMPUTE
#undef PROMOTE

  // ---- y1 tile -> LDS (overlays A buffers; fenced above) ----
  // C/D layout: col = lane&15, row = (lane>>4)*4 + reg
  double* y1s = dsm;
#pragma unroll
  for (int m = 0; m < 4; ++m)
#pragma unroll
    for (int q = 0; q < 4; ++q) {
      const int t = 16 * m + lg * 4 + q;
      if (t < T1) y1s[t * 64 + 16 * w + lr] = accd[m][q];
    }
  __syncthreads();

  // ---- fp64 LIF scan on wave 0 + ballot bit-pack ----
  if (tid < 64) {
    const int o = ow * 64 + tid;
    const bool valid = o < HID;
    const double bias = valid ? (double)b1v[o] : 0.0;
    u32* bits = gbits + (size_t)b * 510;
    double mem = 0.0;
    for (int t = 0; t < T1; ++t) {
      const double x = y1s[t * 64 + tid] + bias;
      const double reset = (mem > 1.0) ? 1.0 : 0.0;
      mem = __dsub_rn(__dadd_rn(__dmul_rn(0.9, mem), x), reset);
      const unsigned long long mk = __ballot(valid && (mem > 1.0));
      if (tid == 0)  bits[t * 10 + 2 * ow]     = (u32)mk;
      if (tid == 32) bits[t * 10 + 2 * ow + 1] = (u32)(mk >> 32);
    }
  }
}

// ===========================================================================
// Fallback layer-1 (fp32, gauss in-kernel) — round-1/2 proven path.
// ===========================================================================
__device__ __forceinline__ void layer1_tile_g(
    int b, int ow, int tid,
    const float* __restrict__ data, const float* __restrict__ W1,
    const float* __restrict__ P1, const float* __restrict__ b1v,
    double* __restrict__ dsm, u32* __restrict__ bits)
{
  float* Bsf = (float*)dsm;
  float* As  = (float*)dsm + 2880;

  const int ty = tid >> 5;
  const int tx = tid & 31;
  const int r0 = ty << 3;
  const int c0 = tx << 1;

  const float* abase = data + (size_t)b * (TT * CIN);

  const int slot = tid >> 2;
  const int pair = tid & 3;
  const int tp   = slot - 5;

  const int isub = tid & 7;
  const int oA = tid >> 3;
  const int oB = oA + 32;
  const int boA = ow * 64 + oA;
  const int boB = ow * 64 + oB;
  const bool vB = boB < HID;

  double acc[8][2];
#pragma unroll
  for (int r = 0; r < 8; ++r) { acc[r][0] = 0.0; acc[r][1] = 0.0; }

  float2 aA = make_float2(0.f, 0.f);
  float wA = 0.f, pA = 0.f, wB = 0.f, pB = 0.f;
  if (tid < 220 && tp >= 0)
    aA = *(const float2*)(abase + (size_t)tp * CIN + 2 * pair);
  wA = W1[(size_t)boA * CIN + isub];
  pA = P1[(size_t)boA * CIN + isub];
  if (vB) {
    wB = W1[(size_t)boB * CIN + isub];
    pB = P1[(size_t)boB * CIN + isub];
  }

  for (int i0 = 0; i0 < CIN; i0 += 8) {
    if (tid < 220) {
      As[(2 * pair) * 80 + slot]     = aA.x;
      As[(2 * pair + 1) * 80 + slot] = aA.y;
    }
    {
      const float c  = pA + 2.0f;
      const float E0 = __expf(-0.125f * c * c);
      const float U  = __expf(0.25f * c);
      const float u2 = U * U;
      const float e0 = E0;
      const float e1 = E0 * U * EK1f;
      const float e2 = E0 * u2 * EK2f;
      const float e3 = E0 * (u2 * U) * EK3f;
      const float e4 = E0 * (u2 * u2) * EK4f;
      const float inv = 1.0f / (((((e0 + e1) + e2) + e3) + e4) + 1e-7f);
      float* bp = Bsf + isub * 72 + oA;
      bp[0]    = wA * (e0 * inv);
      bp[576]  = wA * (e1 * inv);
      bp[1152] = wA * (e2 * inv);
      bp[1728] = wA * (e3 * inv);
      bp[2304] = wA * (e4 * inv);
    }
    {
      const float c  = pB + 2.0f;
      const float E0 = __expf(-0.125f * c * c);
      const float U  = __expf(0.25f * c);
      const float u2 = U * U;
      const float e0 = E0;
      const float e1 = E0 * U * EK1f;
      const float e2 = E0 * u2 * EK2f;
      const float e3 = E0 * (u2 * U) * EK3f;
      const float e4 = E0 * (u2 * u2) * EK4f;
      const float inv = 1.0f / (((((e0 + e1) + e2) + e3) + e4) + 1e-7f);
      float* bp = Bsf + isub * 72 + oB;
      bp[0]    = wB * (e0 * inv);
      bp[576]  = wB * (e1 * inv);
      bp[1152] = wB * (e2 * inv);
      bp[1728] = wB * (e3 * inv);
      bp[2304] = wB * (e4 * inv);
    }
    __syncthreads();

    const int i0n = i0 + 8;
    if (i0n < CIN) {
      if (tid < 220 && tp >= 0)
        aA = *(const float2*)(abase + (size_t)tp * CIN + i0n + 2 * pair);
      wA = W1[(size_t)boA * CIN + i0n + isub];
      pA = P1[(size_t)boA * CIN + i0n + isub];
      if (vB) {
        wB = W1[(size_t)boB * CIN + i0n + isub];
        pB = P1[(size_t)boB * CIN + i0n + isub];
      }
    }

    float accf[8][2];
#pragma unroll
    for (int r = 0; r < 8; ++r) { accf[r][0] = 0.f; accf[r][1] = 0.f; }
#pragma unroll
    for (int kk = 0; kk < 8; ++kk) {
      const float* ap = &As[kk * 80 + r0];
      const float4 a0 = *(const float4*)(ap);
      const float4 a1 = *(const float4*)(ap + 4);
      const float4 a2 = *(const float4*)(ap + 8);
      float av[12];
      av[0] = a0.x; av[1] = a0.y; av[2]  = a0.z; av[3]  = a0.w;
      av[4] = a1.x; av[5] = a1.y; av[6]  = a1.z; av[7]  = a1.w;
      av[8] = a2.x; av[9] = a2.y; av[10] = a2.z; av[11] = a2.w;
      float bv[KS][2];
#pragma unroll
      for (int k = 0; k < KS; ++k) {
        const float2 bb = *(const float2*)&Bsf[(k * 8 + kk) * 72 + c0];
        bv[k][0] = bb.x; bv[k][1] = bb.y;
      }
#pragma unroll
      for (int k = 0; k < KS; ++k)
#pragma unroll
        for (int r = 0; r < 8; ++r) {
          accf[r][0] = fmaf(av[r + k], bv[k][0], accf[r][0]);
          accf[r][1] = fmaf(av[r + k], bv[k][1], accf[r][1]);
        }
    }
#pragma unroll
    for (int r = 0; r < 8; ++r) {
      acc[r][0] += (double)accf[r][0];
      acc[r][1] += (double)accf[r][1];
    }
    __syncthreads();
  }

  double* y1s = dsm;
#pragma unroll
  for (int r = 0; r < 8; ++r) {
    const int t = r0 + r;
    if (t < T1) {
      y1s[t * 64 + c0]     = acc[r][0];
      y1s[t * 64 + c0 + 1] = acc[r][1];
    }
  }
  __syncthreads();

  if (tid < 64) {
    const int o = ow * 64 + tid;
    const bool valid = o < HID;
    const double bias = valid ? (double)b1v[o] : 0.0;
    double mem = 0.0;
    for (int t = 0; t < T1; ++t) {
      const double x = y1s[t * 64 + tid] + bias;
      const double reset = (mem > 1.0) ? 1.0 : 0.0;
      mem = __dsub_rn(__dadd_rn(__dmul_rn(0.9, mem), x), reset);
      const unsigned long long mk = __ballot(valid && (mem > 1.0));
      if (tid == 0)  bits[t * 10 + 2 * ow]     = (u32)mk;
      if (tid == 32) bits[t * 10 + 2 * ow + 1] = (u32)(mk >> 32);
    }
  }
  __syncthreads();
}

// ---------------------------------------------------------------------------
// Layer-2 conv + LIF2 (fp32), spike bits already in LDS at smem+15000.
// ---------------------------------------------------------------------------
__device__ __forceinline__ void layer2_lif2(
    int b, int tid, float* smem,
    const float* __restrict__ W2, const float* __restrict__ P2,
    const float* __restrict__ b2, float* __restrict__ out)
{
  float* K2s = smem;
  const u32* lbits = (const u32*)(smem + 15000);
  float* y2s = smem + 15510;

  for (int idx = tid; idx < NOUT * HID; idx += 256) {
    const int o = idx / HID, i = idx % HID;
    const float w = W2[idx], p = P2[idx];
    const float c = p + 2.0f;
    float e[KS], s = 0.f;
#pragma unroll
    for (int k = 0; k < KS; ++k) {
      const float d = ((float)k - c) * 0.5f;
      e[k] = __expf(-0.5f * d * d);
      s += e[k];
    }
    const float denom = s + 1e-7f;
#pragma unroll
    for (int k = 0; k < KS; ++k)
      K2s[(o * KS + k) * HID + i] = w * (e[k] / denom);
  }
  __syncthreads();                    // also fences lbits population

  for (int task = tid; task < T2 * NOUT; task += 256) {
    const int t2 = task / NOUT, o = task % NOUT;
    float acc = b2[o];
#pragma unroll
    for (int k = 0; k < KS; ++k) {
      const int tp = t2 + k - KS;
      if (tp < 0 || tp >= T1) continue;
      const float* kr = K2s + (o * KS + k) * HID;
      const u32* br = lbits + tp * 10;
      for (int i = 0; i < HID; ++i)
        acc = fmaf((float)((br[i >> 5] >> (i & 31)) & 1u), kr[i], acc);
    }
    y2s[task] = acc;
  }
  __syncthreads();

  if (tid < NOUT) {
    float mem = 0.f;
    for (int t = 0; t < T2; ++t) {
      const float x = y2s[t * NOUT + tid];
      const float reset = (mem > 1.0f) ? 1.0f : 0.0f;
      mem = __fsub_rn(__fadd_rn(__fmul_rn(0.9f, mem), x), reset);
      out[(size_t)t * (BSZ * NOUT) + b * NOUT + tid] = (mem > 1.0f) ? 1.0f : 0.0f;
      out[(size_t)T2 * BSZ * NOUT + (size_t)t * (BSZ * NOUT) + b * NOUT + tid] = mem;
    }
  }
}

// ---------------- split-path kernels ----------------------------------------
__global__ __launch_bounds__(256) void snn_l1(
    const float* __restrict__ data, const float* __restrict__ W1,
    const float* __restrict__ P1, const float* __restrict__ b1v,
    u32* __restrict__ gbits)
{
  __shared__ double dsm[3264];
  const int ow = blockIdx.x, b = blockIdx.y;
  layer1_tile_g(b, ow, threadIdx.x, data, W1, P1, b1v, dsm,
                gbits + (size_t)b * 510);
}

__global__ __launch_bounds__(256) void snn_l2k(
    const u32* __restrict__ gbits,
    const float* __restrict__ W2, const float* __restrict__ P2,
    const float* __restrict__ b2, float* __restrict__ out)
{
  __shared__ float smem[16030];
  const int b = blockIdx.x, tid = threadIdx.x;
  u32* lbits = (u32*)(smem + 15000);
  for (int i = tid; i < 510; i += 256) lbits[i] = gbits[(size_t)b * 510 + i];
  layer2_lif2(b, tid, smem, W2, P2, b2, out);
}

// ---------------- zero-workspace fallback -----------------------------------
__global__ __launch_bounds__(256) void snn_mono(
    const float* __restrict__ data, const float* __restrict__ W1,
    const float* __restrict__ P1, const float* __restrict__ b1v,
    const float* __restrict__ W2, const float* __restrict__ P2,
    const float* __restrict__ b2, float* __restrict__ out)
{
  __shared__ double dsm[8015];
  const int b = blockIdx.x, tid = threadIdx.x;
  u32* lbits = (u32*)((float*)dsm + 15000);
  for (int ow = 0; ow < 5; ++ow)
    layer1_tile_g(b, ow, tid, data, W1, P1, b1v, dsm, lbits);
  layer2_lif2(b, tid, (float*)dsm, W2, P2, b2, out);
}

// ---------------- launcher --------------------------------------------------
extern "C" void kernel_launch(void* const* d_in, const int* in_sizes, int n_in,
                              void* d_out, int out_size, void* d_ws, size_t ws_size,
                              hipStream_t stream) {
  const float* data = (const float*)d_in[0];
  const float* W1   = (const float*)d_in[1];
  const float* P1   = (const float*)d_in[2];
  const float* b1v  = (const float*)d_in[3];
  const float* W2   = (const float*)d_in[4];
  const float* P2   = (const float*)d_in[5];
  const float* b2   = (const float*)d_in[6];
  float* out = (float*)d_out;

  const size_t BITS_BYTES = (size_t)BSZ * T1 * 10 * sizeof(u32);   // 261,120 B
  const size_t K1_OFF = 262144;                                     // 256 KiB
  const size_t K1BF_BYTES = (size_t)5 * NC32 * KFRAG_U * 2;         // 14,950,400
  const size_t NEED_M = K1_OFF + K1BF_BYTES;                        // ~15.2 MB

  if (ws_size >= NEED_M) {
    u32* gbits = (u32*)d_ws;
    u16* K1bf  = (u16*)((char*)d_ws + K1_OFF);
    snn_prepm<<<dim3(NC32, 5), 256, 0, stream>>>(W1, P1, K1bf);
    snn_l1m<<<640, 256, 0, stream>>>(data, K1bf, b1v, gbits);
    snn_l2k<<<BSZ, 256, 0, stream>>>(gbits, W2, P2, b2, out);
  } else if (ws_size >= BITS_BYTES) {
    u32* gbits = (u32*)d_ws;
    snn_l1<<<dim3(5, BSZ), 256, 0, stream>>>(data, W1, P1, b1v, gbits);
    snn_l2k<<<BSZ, 256, 0, stream>>>(gbits, W2, P2, b2, out);
  } else {
    snn_mono<<<BSZ, 256, 0, stream>>>(data, W1, P1, b1v, W2, P2, b2, out);
  }
}

// Round 7
// 444.745 us; speedup vs baseline: 1.0429x; 1.0429x over previous
//
#include <hip/hip_runtime.h>

// Problem constants
#define BSZ  128
#define TT   50
#define CIN  2312
#define HID  300
#define NOUT 10
#define KS   5
#define T1   51          // (TT+5) - KS + 1
#define T2   52          // (T1+5) - KS + 1

#define NC32 73          // ceil(CIN/32) K-chunks of 32
#define KFRAG_U 20480    // u16 units per (ow,chunk): 5k * 4nt * 2h * 512

typedef unsigned int u32;
typedef unsigned short u16;
typedef __attribute__((ext_vector_type(8))) short s16x8;   // 8 bf16 (4 VGPRs)
typedef __attribute__((ext_vector_type(4))) float f32x4;   // MFMA C/D

// exp(-k^2/8) constants, k=1..4 (fp32)
#define EK1f 0.88249690258459546f
#define EK2f 0.60653065971263342f
#define EK3f 0.32465246735834974f
#define EK4f 0.13533528323661270f

static __device__ __forceinline__ u16 bfhi(float x) {
  u32 u = __float_as_uint(x);
  return (u16)((u + 0x7fffu + ((u >> 16) & 1u)) >> 16);   // RNE bf16
}
static __device__ __forceinline__ float bf2f(u16 h) {
  return __uint_as_float(((u32)h) << 16);
}

// ===========================================================================
// prep: synthesize gauss kernel once, split into bf16 hi/lo, in exact MFMA
// B-fragment order: [ow][chunk][k][nt][h][lane][8] (frag = 64 lanes x 16 B).
// ===========================================================================
__global__ __launch_bounds__(256) void snn_prepm(
    const float* __restrict__ W1, const float* __restrict__ P1,
    u16* __restrict__ K1bf)
{
  const int c  = blockIdx.x;          // 0..72
  const int ow = blockIdx.y;          // 0..4
  const int tid = threadIdx.x;
  const int nt = tid >> 6, ll = tid & 63;
  const int g = ll >> 4, lr = ll & 15;
  const int o  = ow * 64 + nt * 16 + lr;
  const int ib = c * 32 + g * 8;

  s16x8 hv[5], lv[5];
#pragma unroll
  for (int k = 0; k < 5; ++k)
#pragma unroll
    for (int j = 0; j < 8; ++j) { hv[k][j] = 0; lv[k][j] = 0; }

  if (o < HID) {
    const float* wrow = W1 + (size_t)o * CIN;
    const float* prow = P1 + (size_t)o * CIN;
#pragma unroll
    for (int j = 0; j < 8; ++j) {
      const int i = ib + j;
      if (i < CIN) {
        const float w1 = wrow[i], p1 = prow[i];
        const float cc = p1 + 2.0f;
        const float E0 = __expf(-0.125f * cc * cc);
        const float U  = __expf(0.25f * cc);
        const float u2 = U * U;
        const float e0 = E0;
        const float e1 = E0 * U * EK1f;
        const float e2 = E0 * u2 * EK2f;
        const float e3 = E0 * (u2 * U) * EK3f;
        const float e4 = E0 * (u2 * u2) * EK4f;
        const float inv = 1.0f / (((((e0 + e1) + e2) + e3) + e4) + 1e-7f);
        const float vk[5] = { w1 * (e0 * inv), w1 * (e1 * inv),
                              w1 * (e2 * inv), w1 * (e3 * inv),
                              w1 * (e4 * inv) };
#pragma unroll
        for (int k = 0; k < 5; ++k) {
          const u16 h = bfhi(vk[k]);
          const u16 lo = bfhi(vk[k] - bf2f(h));
          hv[k][j] = (short)h; lv[k][j] = (short)lo;
        }
      }
    }
  }
  u16* base = K1bf + ((size_t)ow * NC32 + c) * KFRAG_U + nt * 1024 + ll * 8;
#pragma unroll
  for (int k = 0; k < 5; ++k) {
    *(s16x8*)(base + k * 4096)       = hv[k];
    *(s16x8*)(base + k * 4096 + 512) = lv[k];
  }
}

// ===========================================================================
// Layer-1 MFMA path, v4 (= round-5 2x2 skeleton + 4-slot A ring).
// Per block (ow,b): C[64 t][64 o], mfma_f32_16x16x32_bf16, 3-term bf16 split
// (ah*bh + al*bh + ah*bl), fp64 promotion once per chunk-pair.
// Waves 2x2: wave (wr,wc) owns rows 32wr..+31, cols 32wc..+31
//   -> 3 MFMAs per A-frag ds_read (the v3 1x4 grid halved this: reverted).
// A: 64(+4 pad)-slot time window x 32 i, bf16 hi/lo, 4-slot RING in LDS,
//    natural stride-80B banking (NO xor swizzle — round-6 lesson: the
//    non-pow2 stride is already an 8-start spread; xor collapsed it to 4).
//    Two chunks staged per iteration -> ONE barrier per chunk-pair
//    (38 vmcnt(0) drains instead of 73).
// B: 20 frags/wave in registers, rolling per-tap reload after last use;
//    within a pair the odd chunk's reloads are covered by a full chunk of
//    MFMA instead of hitting a barrier.
// XCD swizzle: ow-major per XCD (each XCD sees 1-2 ow of K1bf: L2-resident).
// LDS: ring 4 x 5440 u16 = 43520 B; y1s double[51][64] overlays after loop.
// ===========================================================================
__global__ __launch_bounds__(256, 2) void snn_l1m(
    const float* __restrict__ data, const u16* __restrict__ K1bf,
    const float* __restrict__ b1v, u32* __restrict__ gbits)
{
  __shared__ __align__(16) double dsm[5440];   // 43520 B
  u16* A16 = (u16*)dsm;

  const int tid = threadIdx.x;
  const int bid = blockIdx.x;
  const int rnk = (bid & 7) * 80 + (bid >> 3);   // bijective, 640 = 8*80
  const int ow = rnk >> 7;                        // 0..4 (ow-major per XCD)
  const int b  = rnk & 127;

  const int w  = tid >> 6, l = tid & 63;
  const int lr = l & 15, lg = l >> 4;
  const int wr = w >> 1, wc = w & 1;
  const int abase_u = (32 * wr + lr) * 40 + lg * 8;   // A-frag base (u16)

  const float* dbase = data + (size_t)b * (TT * CIN);
  const u16* kbn = K1bf + (size_t)ow * NC32 * KFRAG_U + l * 8;
  const int ntg0 = wc * 2, ntg1 = wc * 2 + 1;

  // A staging thread mapping: slot s1 (0..63), i-group j4 (0..3)
  const int s1 = tid >> 2;
  const int j4 = tid & 3;
  const int tp = s1 - 5;
  const bool avld = (tp >= 0) && (tp < TT);
  const float* aptr = dbase + (size_t)(avld ? tp : 0) * CIN + j4 * 8;

  // ---- zero pad rows 64..67 (tap overhang) in all 4 ring slots, hi+lo ----
  if (tid < 160) {
    s16x8 z;
#pragma unroll
    for (int j = 0; j < 8; ++j) z[j] = 0;
    const int buf = tid / 40, half = (tid / 20) & 1, off = (tid % 20) * 8;
    *(s16x8*)(A16 + buf * 5440 + half * 2720 + 2560 + off) = z;
  }

  // ---- B frag registers: 20 per wave, rolling reload ----
  s16x8 bh[5][2], bl[5][2];
#pragma unroll
  for (int k = 0; k < 5; ++k) {
    const u16* cb_ = kbn + k * 4096;
    bh[k][0] = *(const s16x8*)(cb_ + ntg0 * 1024);
    bh[k][1] = *(const s16x8*)(cb_ + ntg1 * 1024);
    bl[k][0] = *(const s16x8*)(cb_ + ntg0 * 1024 + 512);
    bl[k][1] = *(const s16x8*)(cb_ + ntg1 * 1024 + 512);
  }

#define LOADA(RA0, RA1, CC)                                                   \
  {                                                                           \
    const int cn_ = ((CC) <= 72) ? (CC) : 72;                                 \
    const bool iv_ = avld && ((CC) <= 72) && ((cn_ < 72) || (j4 == 0));       \
    const float* pp_ = aptr + (size_t)cn_ * 32;                               \
    RA0 = iv_ ? *(const float4*)(pp_)     : make_float4(0.f, 0.f, 0.f, 0.f);  \
    RA1 = iv_ ? *(const float4*)(pp_ + 4) : make_float4(0.f, 0.f, 0.f, 0.f);  \
  }

#define STAGE_A(CC, RA0, RA1)                                                 \
  if ((CC) <= 72) {                                                           \
    const float f_[8] = { RA0.x, RA0.y, RA0.z, RA0.w,                         \
                          RA1.x, RA1.y, RA1.z, RA1.w };                       \
    s16x8 hv_, lv_;                                                           \
    _Pragma("unroll")                                                         \
    for (int j = 0; j < 8; ++j) {                                             \
      const u16 h_ = bfhi(f_[j]);                                             \
      hv_[j] = (short)h_;                                                     \
      lv_[j] = (short)bfhi(f_[j] - bf2f(h_));                                 \
    }                                                                         \
    u16* bn_ = A16 + ((CC) & 3) * 5440;                                       \
    const int woff_ = s1 * 40 + j4 * 8;                                       \
    *(s16x8*)(bn_ + woff_) = hv_;                                             \
    *(s16x8*)(bn_ + 2720 + woff_) = lv_;                                      \
  }

#define COMPUTE(CC, RC)                                                       \
  {                                                                           \
    const u16* bc_ = A16 + ((CC) & 3) * 5440;                                 \
    _Pragma("unroll")                                                         \
    for (int k = 0; k < 5; ++k) {                                             \
      const s16x8 ah0 = *(const s16x8*)(bc_ + abase_u + k * 40);              \
      const s16x8 al0 = *(const s16x8*)(bc_ + 2720 + abase_u + k * 40);       \
      const s16x8 ah1 = *(const s16x8*)(bc_ + abase_u + (16 + k) * 40);       \
      const s16x8 al1 = *(const s16x8*)(bc_ + 2720 + abase_u + (16 + k) * 40);\
      accf[0][0] = __builtin_amdgcn_mfma_f32_16x16x32_bf16(ah0, bh[k][0], accf[0][0], 0, 0, 0); \
      accf[0][0] = __builtin_amdgcn_mfma_f32_16x16x32_bf16(al0, bh[k][0], accf[0][0], 0, 0, 0); \
      accf[0][0] = __builtin_amdgcn_mfma_f32_16x16x32_bf16(ah0, bl[k][0], accf[0][0], 0, 0, 0); \
      accf[0][1] = __builtin_amdgcn_mfma_f32_16x16x32_bf16(ah0, bh[k][1], accf[0][1], 0, 0, 0); \
      accf[0][1] = __builtin_amdgcn_mfma_f32_16x16x32_bf16(al0, bh[k][1], accf[0][1], 0, 0, 0); \
      accf[0][1] = __builtin_amdgcn_mfma_f32_16x16x32_bf16(ah0, bl[k][1], accf[0][1], 0, 0, 0); \
      accf[1][0] = __builtin_amdgcn_mfma_f32_16x16x32_bf16(ah1, bh[k][0], accf[1][0], 0, 0, 0); \
      accf[1][0] = __builtin_amdgcn_mfma_f32_16x16x32_bf16(al1, bh[k][0], accf[1][0], 0, 0, 0); \
      accf[1][0] = __builtin_amdgcn_mfma_f32_16x16x32_bf16(ah1, bl[k][0], accf[1][0], 0, 0, 0); \
      accf[1][1] = __builtin_amdgcn_mfma_f32_16x16x32_bf16(ah1, bh[k][1], accf[1][1], 0, 0, 0); \
      accf[1][1] = __builtin_amdgcn_mfma_f32_16x16x32_bf16(al1, bh[k][1], accf[1][1], 0, 0, 0); \
      accf[1][1] = __builtin_amdgcn_mfma_f32_16x16x32_bf16(ah1, bl[k][1], accf[1][1], 0, 0, 0); \
      if ((RC) <= 72) {                                                       \
        const u16* cb_ = kbn + (size_t)(RC) * KFRAG_U + k * 4096;             \
        bh[k][0] = *(const s16x8*)(cb_ + ntg0 * 1024);                        \
        bh[k][1] = *(const s16x8*)(cb_ + ntg1 * 1024);                        \
        bl[k][0] = *(const s16x8*)(cb_ + ntg0 * 1024 + 512);                  \
        bl[k][1] = *(const s16x8*)(cb_ + ntg1 * 1024 + 512);                  \
      }                                                                       \
    }                                                                         \
  }

#define PROMOTE()                                                             \
  _Pragma("unroll")                                                           \
  for (int m = 0; m < 2; ++m)                                                 \
    _Pragma("unroll")                                                         \
    for (int n = 0; n < 2; ++n)                                               \
      _Pragma("unroll")                                                       \
      for (int q = 0; q < 4; ++q) {                                           \
        accd[m][n][q] += (double)accf[m][n][q];                               \
        accf[m][n][q] = 0.f;                                                  \
      }

  f32x4 accf[2][2];
  double accd[2][2][4];
#pragma unroll
  for (int m = 0; m < 2; ++m)
#pragma unroll
    for (int n = 0; n < 2; ++n)
#pragma unroll
      for (int q = 0; q < 4; ++q) { accf[m][n][q] = 0.f; accd[m][n][q] = 0.0; }

  // ---- prologue: stage chunks 0,1; issue loads for 2,3 ----
  float4 raA0, raA1, raB0, raB1;
  LOADA(raA0, raA1, 0);
  LOADA(raB0, raB1, 1);
  STAGE_A(0, raA0, raA1);
  STAGE_A(1, raB0, raB1);
  LOADA(raA0, raA1, 2);
  LOADA(raB0, raB1, 3);
  __syncthreads();

  // ---- main loop: 36 pairs (chunks 0..71), one barrier per pair ----
  for (int pi = 0; pi < 36; ++pi) {
    const int c0 = 2 * pi;
    STAGE_A(c0 + 2, raA0, raA1);
    STAGE_A(c0 + 3, raB0, raB1);
    LOADA(raA0, raA1, c0 + 4);
    LOADA(raB0, raB1, c0 + 5);
    COMPUTE(c0,     c0 + 1);     // even chunk; reload B <- c0+1
    COMPUTE(c0 + 1, c0 + 2);     // odd chunk;  reload B <- c0+2
    PROMOTE();
    __syncthreads();
  }
  // tail chunk 72 (slot 0, staged at pi=35; B loaded during chunk 71)
  COMPUTE(72, 73);
  PROMOTE();
  __syncthreads();

#undef LOADA
#undef STAGE_A
#undef COMPUTE
#undef PROMOTE

  // ---- y1 tile -> LDS (overlays ring; fenced above) ----
  // C/D layout: col = lane&15, row = (lane>>4)*4 + reg
  double* y1s = dsm;
#pragma unroll
  for (int m = 0; m < 2; ++m)
#pragma unroll
    for (int n = 0; n < 2; ++n)
#pragma unroll
      for (int q = 0; q < 4; ++q) {
        const int t = 32 * wr + 16 * m + lg * 4 + q;
        if (t < T1) y1s[t * 64 + 32 * wc + 16 * n + lr] = accd[m][n][q];
      }
  __syncthreads();

  // ---- fp64 LIF scan on wave 0 + ballot bit-pack ----
  if (tid < 64) {
    const int o = ow * 64 + tid;
    const bool valid = o < HID;
    const double bias = valid ? (double)b1v[o] : 0.0;
    u32* bits = gbits + (size_t)b * 510;
    double mem = 0.0;
    for (int t = 0; t < T1; ++t) {
      const double x = y1s[t * 64 + tid] + bias;
      const double reset = (mem > 1.0) ? 1.0 : 0.0;
      mem = __dsub_rn(__dadd_rn(__dmul_rn(0.9, mem), x), reset);
      const unsigned long long mk = __ballot(valid && (mem > 1.0));
      if (tid == 0)  bits[t * 10 + 2 * ow]     = (u32)mk;
      if (tid == 32) bits[t * 10 + 2 * ow + 1] = (u32)(mk >> 32);
    }
  }
}

// ===========================================================================
// Fallback layer-1 (fp32, gauss in-kernel) — round-1/2 proven path.
// ===========================================================================
__device__ __forceinline__ void layer1_tile_g(
    int b, int ow, int tid,
    const float* __restrict__ data, const float* __restrict__ W1,
    const float* __restrict__ P1, const float* __restrict__ b1v,
    double* __restrict__ dsm, u32* __restrict__ bits)
{
  float* Bsf = (float*)dsm;
  float* As  = (float*)dsm + 2880;

  const int ty = tid >> 5;
  const int tx = tid & 31;
  const int r0 = ty << 3;
  const int c0 = tx << 1;

  const float* abase = data + (size_t)b * (TT * CIN);

  const int slot = tid >> 2;
  const int pair = tid & 3;
  const int tp   = slot - 5;

  const int isub = tid & 7;
  const int oA = tid >> 3;
  const int oB = oA + 32;
  const int boA = ow * 64 + oA;
  const int boB = ow * 64 + oB;
  const bool vB = boB < HID;

  double acc[8][2];
#pragma unroll
  for (int r = 0; r < 8; ++r) { acc[r][0] = 0.0; acc[r][1] = 0.0; }

  float2 aA = make_float2(0.f, 0.f);
  float wA = 0.f, pA = 0.f, wB = 0.f, pB = 0.f;
  if (tid < 220 && tp >= 0)
    aA = *(const float2*)(abase + (size_t)tp * CIN + 2 * pair);
  wA = W1[(size_t)boA * CIN + isub];
  pA = P1[(size_t)boA * CIN + isub];
  if (vB) {
    wB = W1[(size_t)boB * CIN + isub];
    pB = P1[(size_t)boB * CIN + isub];
  }

  for (int i0 = 0; i0 < CIN; i0 += 8) {
    if (tid < 220) {
      As[(2 * pair) * 80 + slot]     = aA.x;
      As[(2 * pair + 1) * 80 + slot] = aA.y;
    }
    {
      const float c  = pA + 2.0f;
      const float E0 = __expf(-0.125f * c * c);
      const float U  = __expf(0.25f * c);
      const float u2 = U * U;
      const float e0 = E0;
      const float e1 = E0 * U * EK1f;
      const float e2 = E0 * u2 * EK2f;
      const float e3 = E0 * (u2 * U) * EK3f;
      const float e4 = E0 * (u2 * u2) * EK4f;
      const float inv = 1.0f / (((((e0 + e1) + e2) + e3) + e4) + 1e-7f);
      float* bp = Bsf + isub * 72 + oA;
      bp[0]    = wA * (e0 * inv);
      bp[576]  = wA * (e1 * inv);
      bp[1152] = wA * (e2 * inv);
      bp[1728] = wA * (e3 * inv);
      bp[2304] = wA * (e4 * inv);
    }
    {
      const float c  = pB + 2.0f;
      const float E0 = __expf(-0.125f * c * c);
      const float U  = __expf(0.25f * c);
      const float u2 = U * U;
      const float e0 = E0;
      const float e1 = E0 * U * EK1f;
      const float e2 = E0 * u2 * EK2f;
      const float e3 = E0 * (u2 * U) * EK3f;
      const float e4 = E0 * (u2 * u2) * EK4f;
      const float inv = 1.0f / (((((e0 + e1) + e2) + e3) + e4) + 1e-7f);
      float* bp = Bsf + isub * 72 + oB;
      bp[0]    = wB * (e0 * inv);
      bp[576]  = wB * (e1 * inv);
      bp[1152] = wB * (e2 * inv);
      bp[1728] = wB * (e3 * inv);
      bp[2304] = wB * (e4 * inv);
    }
    __syncthreads();

    const int i0n = i0 + 8;
    if (i0n < CIN) {
      if (tid < 220 && tp >= 0)
        aA = *(const float2*)(abase + (size_t)tp * CIN + i0n + 2 * pair);
      wA = W1[(size_t)boA * CIN + i0n + isub];
      pA = P1[(size_t)boA * CIN + i0n + isub];
      if (vB) {
        wB = W1[(size_t)boB * CIN + i0n + isub];
        pB = P1[(size_t)boB * CIN + i0n + isub];
      }
    }

    float accf[8][2];
#pragma unroll
    for (int r = 0; r < 8; ++r) { accf[r][0] = 0.f; accf[r][1] = 0.f; }
#pragma unroll
    for (int kk = 0; kk < 8; ++kk) {
      const float* ap = &As[kk * 80 + r0];
      const float4 a0 = *(const float4*)(ap);
      const float4 a1 = *(const float4*)(ap + 4);
      const float4 a2 = *(const float4*)(ap + 8);
      float av[12];
      av[0] = a0.x; av[1] = a0.y; av[2]  = a0.z; av[3]  = a0.w;
      av[4] = a1.x; av[5] = a1.y; av[6]  = a1.z; av[7]  = a1.w;
      av[8] = a2.x; av[9] = a2.y; av[10] = a2.z; av[11] = a2.w;
      float bv[KS][2];
#pragma unroll
      for (int k = 0; k < KS; ++k) {
        const float2 bb = *(const float2*)&Bsf[(k * 8 + kk) * 72 + c0];
        bv[k][0] = bb.x; bv[k][1] = bb.y;
      }
#pragma unroll
      for (int k = 0; k < KS; ++k)
#pragma unroll
        for (int r = 0; r < 8; ++r) {
          accf[r][0] = fmaf(av[r + k], bv[k][0], accf[r][0]);
          accf[r][1] = fmaf(av[r + k], bv[k][1], accf[r][1]);
        }
    }
#pragma unroll
    for (int r = 0; r < 8; ++r) {
      acc[r][0] += (double)accf[r][0];
      acc[r][1] += (double)accf[r][1];
    }
    __syncthreads();
  }

  double* y1s = dsm;
#pragma unroll
  for (int r = 0; r < 8; ++r) {
    const int t = r0 + r;
    if (t < T1) {
      y1s[t * 64 + c0]     = acc[r][0];
      y1s[t * 64 + c0 + 1] = acc[r][1];
    }
  }
  __syncthreads();

  if (tid < 64) {
    const int o = ow * 64 + tid;
    const bool valid = o < HID;
    const double bias = valid ? (double)b1v[o] : 0.0;
    double mem = 0.0;
    for (int t = 0; t < T1; ++t) {
      const double x = y1s[t * 64 + tid] + bias;
      const double reset = (mem > 1.0) ? 1.0 : 0.0;
      mem = __dsub_rn(__dadd_rn(__dmul_rn(0.9, mem), x), reset);
      const unsigned long long mk = __ballot(valid && (mem > 1.0));
      if (tid == 0)  bits[t * 10 + 2 * ow]     = (u32)mk;
      if (tid == 32) bits[t * 10 + 2 * ow + 1] = (u32)(mk >> 32);
    }
  }
  __syncthreads();
}

// ---------------------------------------------------------------------------
// Layer-2 conv + LIF2 (fp32), spike bits already in LDS at smem+15000.
// ---------------------------------------------------------------------------
__device__ __forceinline__ void layer2_lif2(
    int b, int tid, float* smem,
    const float* __restrict__ W2, const float* __restrict__ P2,
    const float* __restrict__ b2, float* __restrict__ out)
{
  float* K2s = smem;
  const u32* lbits = (const u32*)(smem + 15000);
  float* y2s = smem + 15510;

  for (int idx = tid; idx < NOUT * HID; idx += 256) {
    const int o = idx / HID, i = idx % HID;
    const float w = W2[idx], p = P2[idx];
    const float c = p + 2.0f;
    float e[KS], s = 0.f;
#pragma unroll
    for (int k = 0; k < KS; ++k) {
      const float d = ((float)k - c) * 0.5f;
      e[k] = __expf(-0.5f * d * d);
      s += e[k];
    }
    const float denom = s + 1e-7f;
#pragma unroll
    for (int k = 0; k < KS; ++k)
      K2s[(o * KS + k) * HID + i] = w * (e[k] / denom);
  }
  __syncthreads();                    // also fences lbits population

  for (int task = tid; task < T2 * NOUT; task += 256) {
    const int t2 = task / NOUT, o = task % NOUT;
    float acc = b2[o];
#pragma unroll
    for (int k = 0; k < KS; ++k) {
      const int tp = t2 + k - KS;
      if (tp < 0 || tp >= T1) continue;
      const float* kr = K2s + (o * KS + k) * HID;
      const u32* br = lbits + tp * 10;
      for (int i = 0; i < HID; ++i)
        acc = fmaf((float)((br[i >> 5] >> (i & 31)) & 1u), kr[i], acc);
    }
    y2s[task] = acc;
  }
  __syncthreads();

  if (tid < NOUT) {
    float mem = 0.f;
    for (int t = 0; t < T2; ++t) {
      const float x = y2s[t * NOUT + tid];
      const float reset = (mem > 1.0f) ? 1.0f : 0.0f;
      mem = __fsub_rn(__fadd_rn(__fmul_rn(0.9f, mem), x), reset);
      out[(size_t)t * (BSZ * NOUT) + b * NOUT + tid] = (mem > 1.0f) ? 1.0f : 0.0f;
      out[(size_t)T2 * BSZ * NOUT + (size_t)t * (BSZ * NOUT) + b * NOUT + tid] = mem;
    }
  }
}

// ---------------- split-path kernels ----------------------------------------
__global__ __launch_bounds__(256) void snn_l1(
    const float* __restrict__ data, const float* __restrict__ W1,
    const float* __restrict__ P1, const float* __restrict__ b1v,
    u32* __restrict__ gbits)
{
  __shared__ double dsm[3264];
  const int ow = blockIdx.x, b = blockIdx.y;
  layer1_tile_g(b, ow, threadIdx.x, data, W1, P1, b1v, dsm,
                gbits + (size_t)b * 510);
}

__global__ __launch_bounds__(256) void snn_l2k(
    const u32* __restrict__ gbits,
    const float* __restrict__ W2, const float* __restrict__ P2,
    const float* __restrict__ b2, float* __restrict__ out)
{
  __shared__ float smem[16030];
  const int b = blockIdx.x, tid = threadIdx.x;
  u32* lbits = (u32*)(smem + 15000);
  for (int i = tid; i < 510; i += 256) lbits[i] = gbits[(size_t)b * 510 + i];
  layer2_lif2(b, tid, smem, W2, P2, b2, out);
}

// ---------------- zero-workspace fallback -----------------------------------
__global__ __launch_bounds__(256) void snn_mono(
    const float* __restrict__ data, const float* __restrict__ W1,
    const float* __restrict__ P1, const float* __restrict__ b1v,
    const float* __restrict__ W2, const float* __restrict__ P2,
    const float* __restrict__ b2, float* __restrict__ out)
{
  __shared__ double dsm[8015];
  const int b = blockIdx.x, tid = threadIdx.x;
  u32* lbits = (u32*)((float*)dsm + 15000);
  for (int ow = 0; ow < 5; ++ow)
    layer1_tile_g(b, ow, tid, data, W1, P1, b1v, dsm, lbits);
  layer2_lif2(b, tid, (float*)dsm, W2, P2, b2, out);
}

// ---------------- launcher --------------------------------------------------
extern "C" void kernel_launch(void* const* d_in, const int* in_sizes, int n_in,
                              void* d_out, int out_size, void* d_ws, size_t ws_size,
                              hipStream_t stream) {
  const float* data = (const float*)d_in[0];
  const float* W1   = (const float*)d_in[1];
  const float* P1   = (const float*)d_in[2];
  const float* b1v  = (const float*)d_in[3];
  const float* W2   = (const float*)d_in[4];
  const float* P2   = (const float*)d_in[5];
  const float* b2   = (const float*)d_in[6];
  float* out = (float*)d_out;

  const size_t BITS_BYTES = (size_t)BSZ * T1 * 10 * sizeof(u32);   // 261,120 B
  const size_t K1_OFF = 262144;                                     // 256 KiB
  const size_t K1BF_BYTES = (size_t)5 * NC32 * KFRAG_U * 2;         // 14,950,400
  const size_t NEED_M = K1_OFF + K1BF_BYTES;                        // ~15.2 MB

  if (ws_size >= NEED_M) {
    u32* gbits = (u32*)d_ws;
    u16* K1bf  = (u16*)((char*)d_ws + K1_OFF);
    snn_prepm<<<dim3(NC32, 5), 256, 0, stream>>>(W1, P1, K1bf);
    snn_l1m<<<640, 256, 0, stream>>>(data, K1bf, b1v, gbits);
    snn_l2k<<<BSZ, 256, 0, stream>>>(gbits, W2, P2, b2, out);
  } else if (ws_size >= BITS_BYTES) {
    u32* gbits = (u32*)d_ws;
    snn_l1<<<dim3(5, BSZ), 256, 0, stream>>>(data, W1, P1, b1v, gbits);
    snn_l2k<<<BSZ, 256, 0, stream>>>(gbits, W2, P2, b2, out);
  } else {
    snn_mono<<<BSZ, 256, 0, stream>>>(data, W1, P1, b1v, W2, P2, b2, out);
  }
}